// Round 14
// baseline (4623.704 us; speedup 1.0000x reference)
//
#include <hip/hip_runtime.h>
#include <hip/hip_bf16.h>

#define B_    8192
#define D_    2048
#define H_    4096
#define C_    64
#define HALF_ 1024
#define KIN_  1088   // HALF_ + C_

typedef __attribute__((ext_vector_type(8))) short bf16x8;
typedef __attribute__((ext_vector_type(4))) float f32x4;

__device__ __forceinline__ unsigned short f2bf(float f) {
  __hip_bfloat16 h = __float2bfloat16(f);
  return *reinterpret_cast<unsigned short*>(&h);
}

__device__ __forceinline__ void gload16(const void* g, void* s) {
  __builtin_amdgcn_global_load_lds((const __attribute__((address_space(1))) void*)g,
                                   (__attribute__((address_space(3))) void*)s,
                                   16, 0, 0);
}

// W [K,N] fp32 row-major  ->  Wt [N,K] bf16 row-major (transpose + convert)
__global__ void convT(const float* __restrict__ W, unsigned short* __restrict__ Wt,
                      int K, int N) {
  __shared__ float tile[32][33];
  int tx = threadIdx.x & 31, ty = threadIdx.x >> 5;   // 32x8 threads
  int n0 = blockIdx.x * 32, k0 = blockIdx.y * 32;
#pragma unroll
  for (int i = 0; i < 4; ++i)
    tile[ty + i * 8][tx] = W[(size_t)(k0 + ty + i * 8) * N + n0 + tx];
  __syncthreads();
#pragma unroll
  for (int i = 0; i < 4; ++i)
    Wt[(size_t)(n0 + ty + i * 8) * K + k0 + tx] = f2bf(tile[tx][ty + i * 8]);
}

// A0[b, c<1024] = xsrc[b, 2c+par], A0[b, 1024:1088] = condition[b, .]  (bf16)
__global__ void build_act(const float* __restrict__ xsrc, const float* __restrict__ cond,
                          int par, unsigned short* __restrict__ A0) {
  int row = blockIdx.y;
  int col = blockIdx.x * 256 + threadIdx.x;
  if (col >= KIN_) return;
  float v;
  if (col < HALF_) {
    float2 p = ((const float2*)xsrc)[(size_t)row * (D_ / 2) + col];
    v = par ? p.y : p.x;
  } else {
    v = cond[(size_t)row * C_ + (col - HALF_)];
  }
  A0[(size_t)row * KIN_ + col] = f2bf(v);
}

// ---------------------------------------------------------------------------
// R14 = R11 (256x256, 16 waves 4Mx4N of 64x64, BK=32, A+B in LDS, verified
// swizzle / staging / epilogues) + CROSS-WINDOW REGISTER PREFETCH on a
// 4-buffer ring (4 x 32 KiB = 128 KiB):
//   window T: { read frags(T+1) from buf[(T+1)%4] -> other reg set;
//               stage tile T+3 -> buf[(T+3)%4]; MFMA(T) on current set;
//               vmcnt(2); barrier }
// In-wave overlap: MFMA(T) does not depend on the new ds_reads, so they run
// under it; the compiler's lgkmcnt before MFMA(T+1) lands next window.
// Ledger (2 stage-loads/window): end of window T-1 vmcnt(2) drains tile T+1
// (outstanding = T+1:2 + T+2:2), its barrier publishes -> frags(T+1)
// readable during T. Stage target buf[(T+3)%4] holds tile T-1, whose reads
// (issued window T-2) were consumed by MFMA(T-1) before the barrier ending
// window T-1 -> overwrite-safe. Prologue: stage 0,1,2 (6 loads); vmcnt(2)
// drains tile 0,1; barrier; read frags(0). Tails: T=NT-3 vmcnt(0) (drains
// tile NT-1); T=NT-2 barrier only; T=NT-1 nothing.
// Register cost: 2 frag sets (64 VGPR) + acc 64 -> ~150 unified, static
// ping-pong via named sets (rule #20), well under 512/wave at 4 waves/SIMD.
// MODE 0: C = bf16(relu(.+bias)) via per-wave LDS bounce. MODE 1: fused
// coupling epilogue.
// ---------------------------------------------------------------------------
template <int MODE>
__global__ __launch_bounds__(1024, 4)
void gemmk(const unsigned short* __restrict__ A,
           const unsigned short* __restrict__ Bt,
           const float* __restrict__ bias,
           unsigned short* __restrict__ Cout,
           const float* __restrict__ xold, float* __restrict__ xnew,
           float* __restrict__ part, int par,
           int M, int N, int K) {
  __shared__ unsigned short lds[65536];   // 128 KiB = 4-ring; epilogue reuses
  char* ldsb = (char*)lds;
  const int tid = threadIdx.x;
  const int w = tid >> 6, lane = tid & 63;
  const int fr = lane & 15, fq = lane >> 4;
  const int wr = w >> 2, wc = w & 3;          // 4M x 4N waves, wave tile 64x64

  // XCD-aware block swizzle (nwg % 8 == 0 for all our grids)
  const int nbx = N >> 8;
  const int nwg = (int)gridDim.x;
  const int cpx = nwg >> 3;
  const int bid = (int)blockIdx.x;
  const int swz = (bid & 7) * cpx + (bid >> 3);
  const int by = swz / nbx, bx = swz - by * nbx;
  const int m0 = by << 8, n0 = bx << 8;

  // read-side swizzled base offsets within a 32 KiB buffer (A @0, B @16KB)
  const int chunkp = (((fr & 1) << 2) | fq) ^ (fr >> 1);
  const int A0 = (wr * 32 + (fr >> 1)) * 128 + chunkp * 16;
  const int B0 = 16384 + (wc * 32 + (fr >> 1)) * 128 + chunkp * 16;

  // stage-side: inverse-swizzled per-lane global source; linear LDS dest.
  // 1024 threads x 16B = one full 16KB slab per gload16 call.
  const int p = tid >> 3, cph = tid & 7;
  const int clg = cph ^ (p & 7);
  const int rowS = 2 * p + (clg >> 2);
  const int kcolS = (clg & 3) * 8;
  const unsigned short* sA0 = A + (size_t)(m0 + rowS) * K + kcolS;
  const unsigned short* sB0 = Bt + (size_t)(n0 + rowS) * K + kcolS;
  const int dst0 = tid * 16;

// stage one BK=32 tile (A 16KB + B 16KB) into buffer at OFF; advance ptrs
#define STAGE_ALL(OFF) do {                                                  \
    gload16(sA0, ldsb + (OFF) + dst0);                                       \
    gload16(sB0, ldsb + (OFF) + 16384 + dst0);                               \
    sA0 += 32; sB0 += 32;                                                    \
  } while (0)

#define RDF(AV, BV, OFF)                                                     \
    _Pragma("unroll") for (int n = 0; n < 4; ++n)                            \
      BV[n] = *(const bf16x8*)(ldsb + (OFF) + B0 + n * 1024);                \
    _Pragma("unroll") for (int m = 0; m < 4; ++m)                            \
      AV[m] = *(const bf16x8*)(ldsb + (OFF) + A0 + m * 1024);

// window T: read frags(T+1)->NXT, stage T+3, MFMA on CUR, sync, rotate.
// VM: 1 = vmcnt(2)+barrier; 2 = vmcnt(0)+barrier; 0 = barrier only; 3 = none
#define WIN(CA, CB, NA, NB, RD, STG, VM)                                     \
  {                                                                          \
    if (RD) { RDF(NA, NB, rdo) }                                             \
    if (STG) STAGE_ALL(sto);                                                 \
    __builtin_amdgcn_sched_barrier(0);                                       \
    __builtin_amdgcn_s_setprio(1);                                           \
    _Pragma("unroll") for (int m = 0; m < 4; ++m)                            \
      _Pragma("unroll") for (int n = 0; n < 4; ++n)                          \
        acc[m][n] = __builtin_amdgcn_mfma_f32_16x16x32_bf16(                 \
            CA[m], CB[n], acc[m][n], 0, 0, 0);                               \
    __builtin_amdgcn_s_setprio(0);                                           \
    __builtin_amdgcn_sched_barrier(0);                                       \
    if (VM == 1) asm volatile("s_waitcnt vmcnt(2)" ::: "memory");            \
    if (VM == 2) asm volatile("s_waitcnt vmcnt(0)" ::: "memory");            \
    __builtin_amdgcn_sched_barrier(0);                                       \
    if (VM != 3) __builtin_amdgcn_s_barrier();                               \
    rdo = (rdo == 98304) ? 0 : rdo + 32768;                                  \
    sto = (sto == 98304) ? 0 : sto + 32768;                                  \
  }

  f32x4 acc[4][4];
  f32x4 z4 = {0.f, 0.f, 0.f, 0.f};
#pragma unroll
  for (int m = 0; m < 4; ++m)
#pragma unroll
    for (int n = 0; n < 4; ++n) acc[m][n] = z4;

  const int NT = K >> 5;   // BK=32; NT even (34 / 128 / 64), NT >= 6

  bf16x8 avE[4], bvE[4], avO[4], bvO[4];

  // prologue: stage tiles 0,1,2; drain 0,1; publish; read frags(0) -> E
  STAGE_ALL(0);
  STAGE_ALL(32768);
  STAGE_ALL(65536);
  asm volatile("s_waitcnt vmcnt(2)" ::: "memory");
  __builtin_amdgcn_sched_barrier(0);
  __builtin_amdgcn_s_barrier();
  RDF(avE, bvE, 0)
  int rdo = 32768, sto = 98304;   // window 0: read frags(1), stage tile 3

  for (int P = 0; P < (NT - 4) / 2; ++P) {
    WIN(avE, bvE, avO, bvO, 1, 1, 1)   // T even
    WIN(avO, bvO, avE, bvE, 1, 1, 1)   // T odd
  }
  WIN(avE, bvE, avO, bvO, 1, 1, 1)     // T = NT-4: stages tile NT-1
  WIN(avO, bvO, avE, bvE, 1, 0, 2)     // T = NT-3: vmcnt(0) drains NT-1
  WIN(avE, bvE, avO, bvO, 1, 0, 0)     // T = NT-2: read frags(NT-1)
  WIN(avO, bvO, avE, bvE, 0, 0, 3)     // T = NT-1: compute only
#undef WIN
#undef RDF
#undef STAGE_ALL

  // ---- epilogue ---- (C/D frag layout: row = fq*4 + r, col = fr; m89/m91)
  if (MODE == 0) {
    // bf16 + relu via per-wave LDS bounce: wave region w*8192 = [64][128B],
    // chunk ^= fq swizzle (<=2-way = free, R4-verified pattern).
    __builtin_amdgcn_s_barrier();   // all waves done reading ring buffers
#pragma unroll
    for (int m = 0; m < 4; ++m)
#pragma unroll
      for (int n = 0; n < 4; ++n) {
        int gcol = n0 + wc * 64 + n * 16 + fr;
        float bb = bias[gcol];
#pragma unroll
        for (int r = 0; r < 4; ++r) {
          float v = fmaxf(acc[m][n][r] + bb, 0.f);
          int lrow = m * 16 + fq * 4 + r;
          *(unsigned short*)(ldsb + w * 8192 + lrow * 128 + ((n ^ fq) * 32) + fr * 2) = f2bf(v);
        }
      }
    asm volatile("s_waitcnt lgkmcnt(0)" ::: "memory");   // own-wave region only
    __builtin_amdgcn_sched_barrier(0);
    unsigned short* Cb = Cout + (size_t)(m0 + wr * 64) * N + n0 + wc * 64;
    const int sub = lane & 7;
#pragma unroll
    for (int i = 0; i < 8; ++i) {
      int lrow = i * 8 + (lane >> 3);
      int phys = (sub >> 1) ^ ((lrow >> 2) & 3);
      bf16x8 val = *(const bf16x8*)(ldsb + w * 8192 + lrow * 128 + phys * 32 + (sub & 1) * 16);
      *(bf16x8*)(Cb + (size_t)lrow * N + sub * 8) = val;
    }
  } else {
    // fused coupling: even col 2j = S, odd = T (pair via shfl_xor 1);
    // xnew[row][2j+par] = xold[row][2j+par]*exp(S)+T; S partials -> part.
#pragma unroll
    for (int m = 0; m < 4; ++m) {
      float srow[4] = {0.f, 0.f, 0.f, 0.f};
#pragma unroll
      for (int n = 0; n < 4; ++n) {
        int gcol = n0 + wc * 64 + n * 16 + fr;
        float bb = bias[gcol];
#pragma unroll
        for (int r = 0; r < 4; ++r) {
          float v = acc[m][n][r] + bb;
          float vp = __shfl_xor(v, 1);
          if (!(fr & 1)) {
            int grow = m0 + wr * 64 + m * 16 + fq * 4 + r;
            size_t idx = (size_t)grow * N + gcol + par;
            xnew[idx] = xold[idx] * expf(v) + vp;
            srow[r] += v;
          }
        }
      }
#pragma unroll
      for (int r = 0; r < 4; ++r) {
        float s = srow[r];
        s += __shfl_xor(s, 2);
        s += __shfl_xor(s, 4);
        s += __shfl_xor(s, 8);
        if (fr == 0) {
          int grow = m0 + wr * 64 + m * 16 + fq * 4 + r;
          part[(size_t)grow * 32 + bx * 4 + wc] = s;
        }
      }
    }
  }
}

// logdet[row] (= or +=) sum of 32 column-group partials
__global__ void reduce_logdet(const float* __restrict__ P, float* __restrict__ logdet, int add) {
  int row = blockIdx.x * 256 + threadIdx.x;
  float s = 0.f;
#pragma unroll
  for (int g = 0; g < 32; ++g) s += P[(size_t)row * 32 + g];
  logdet[row] = add ? (logdet[row] + s) : s;
}

extern "C" void kernel_launch(void* const* d_in, const int* in_sizes, int n_in,
                              void* d_out, int out_size, void* d_ws, size_t ws_size,
                              hipStream_t stream) {
  const float* z    = (const float*)d_in[0];
  const float* cond = (const float*)d_in[1];
  const float* W1   = (const float*)d_in[4];
  const float* b1   = (const float*)d_in[5];
  const float* W2   = (const float*)d_in[6];
  const float* b2   = (const float*)d_in[7];
  const float* W3   = (const float*)d_in[8];
  const float* b3   = (const float*)d_in[9];

  float* xout   = (float*)d_out;                 // [B, D]
  float* logdet = xout + (size_t)B_ * D_;        // [B]

  // workspace (160 MiB): Wt 32 MiB | H1 64 MiB (h1 / logdet partials) |
  //                      H2 64 MiB (A0 input acts / h2)
  char* ws = (char*)d_ws;
  unsigned short* Wt = (unsigned short*)ws;
  unsigned short* H1 = (unsigned short*)(ws + 33554432);
  unsigned short* H2 = (unsigned short*)(ws + 33554432 + 67108864);
  float* Pp = (float*)H1;          // [B][32] S-partials (H1 free during GEMM3)
  unsigned short* A0 = H2;

  for (int blk = 0; blk < 2; ++blk) {
    const float* W1b = W1 + (size_t)blk * KIN_ * H_;
    const float* W2b = W2 + (size_t)blk * H_ * H_;
    const float* W3b = W3 + (size_t)blk * H_ * D_;
    const float* b1b = b1 + (size_t)blk * H_;
    const float* b2b = b2 + (size_t)blk * H_;
    const float* b3b = b3 + (size_t)blk * D_;
    // identity channels parity 1-blk; transformed channels parity blk.
    const float* xsrc = blk ? xout : z;

    // GEMM1: [B,1088] x [1088,4096]
    convT<<<dim3(H_ / 32, KIN_ / 32), 256, 0, stream>>>(W1b, Wt, KIN_, H_);
    build_act<<<dim3(5, B_), 256, 0, stream>>>(xsrc, cond, 1 - blk, A0);
    gemmk<0><<<dim3((B_ / 256) * (H_ / 256)), 1024, 0, stream>>>(
        A0, Wt, b1b, H1, nullptr, nullptr, nullptr, 0, B_, H_, KIN_);

    // GEMM2: [B,4096] x [4096,4096]
    convT<<<dim3(H_ / 32, H_ / 32), 256, 0, stream>>>(W2b, Wt, H_, H_);
    gemmk<0><<<dim3((B_ / 256) * (H_ / 256)), 1024, 0, stream>>>(
        H1, Wt, b2b, H2, nullptr, nullptr, nullptr, 0, B_, H_, H_);

    // GEMM3: [B,4096] x [4096,2048] with fused coupling epilogue
    convT<<<dim3(D_ / 32, H_ / 32), 256, 0, stream>>>(W3b, Wt, H_, D_);
    gemmk<1><<<dim3((B_ / 256) * (D_ / 256)), 1024, 0, stream>>>(
        H2, Wt, b3b, nullptr, z, xout, Pp, blk, B_, D_, H_);

    reduce_logdet<<<dim3(B_ / 256), 256, 0, stream>>>(Pp, logdet, blk);
  }
}

// Round 16
// 990.858 us; speedup vs baseline: 4.6664x; 4.6664x over previous
//
#include <hip/hip_runtime.h>
#include <hip/hip_bf16.h>

#define B_    8192
#define D_    2048
#define H_    4096
#define C_    64
#define HALF_ 1024
#define KIN_  1088   // HALF_ + C_

typedef __attribute__((ext_vector_type(8))) short bf16x8;
typedef __attribute__((ext_vector_type(4))) float f32x4;

__device__ __forceinline__ unsigned short f2bf(float f) {
  __hip_bfloat16 h = __float2bfloat16(f);
  return *reinterpret_cast<unsigned short*>(&h);
}

__device__ __forceinline__ void gload16(const void* g, void* s) {
  __builtin_amdgcn_global_load_lds((const __attribute__((address_space(1))) void*)g,
                                   (__attribute__((address_space(3))) void*)s,
                                   16, 0, 0);
}

// W [K,N] fp32 row-major  ->  Wt [N,K] bf16 row-major (transpose + convert)
__global__ void convT(const float* __restrict__ W, unsigned short* __restrict__ Wt,
                      int K, int N) {
  __shared__ float tile[32][33];
  int tx = threadIdx.x & 31, ty = threadIdx.x >> 5;   // 32x8 threads
  int n0 = blockIdx.x * 32, k0 = blockIdx.y * 32;
#pragma unroll
  for (int i = 0; i < 4; ++i)
    tile[ty + i * 8][tx] = W[(size_t)(k0 + ty + i * 8) * N + n0 + tx];
  __syncthreads();
#pragma unroll
  for (int i = 0; i < 4; ++i)
    Wt[(size_t)(n0 + ty + i * 8) * K + k0 + tx] = f2bf(tile[tx][ty + i * 8]);
}

// A0[b, c<1024] = xsrc[b, 2c+par], A0[b, 1024:1088] = condition[b, .]  (bf16)
__global__ void build_act(const float* __restrict__ xsrc, const float* __restrict__ cond,
                          int par, unsigned short* __restrict__ A0) {
  int row = blockIdx.y;
  int col = blockIdx.x * 256 + threadIdx.x;
  if (col >= KIN_) return;
  float v;
  if (col < HALF_) {
    float2 p = ((const float2*)xsrc)[(size_t)row * (D_ / 2) + col];
    v = par ? p.y : p.x;
  } else {
    v = cond[(size_t)row * C_ + (col - HALF_)];
  }
  A0[(size_t)row * KIN_ + col] = f2bf(v);
}

// ---------------------------------------------------------------------------
// R16 = R15 resubmitted (infra failure last round, no measurement).
// R11 structure (verified best: 991 us total, GEMM2 226 us, 0 bank
// conflicts, VGPR 64, occupancy 43%) + one free reorder: stage gload_lds
// issued BEFORE the ds_reads inside the window (earlier HBM issue; vmcnt FIFO
// count at window end unchanged).
//
// 256x256 tile, 16 waves (4Mx4N of 64x64), BK=32, 3-buffer 96 KiB LDS ring.
// Window T: [s_barrier; stage T+2 -> buf[(T+2)%3]; read 8 frags from
//            buf[T%3]; 16 MFMA; vmcnt(2)]
// Ledger: stage target holds T-1, whose ds_reads fed MFMA(T-1) before this
// window's entry barrier in every wave -> safe. vmcnt(2) at window end:
// outstanding = T+1(2) + T+2(2) -> drains T+1 (collective after next
// barrier), leaves T+2 in flight. Tail: T=NT-2 no stage + vmcnt(0); T=NT-1
// compute only.
// Register accounting (hard limit learned in R12/R14): 16 waves/CU => 128
// regs/wave; acc 64 + one frag set 32 + addresses ~20 fits; ANY second frag
// set spills to scratch (R12: 2.4GB, R14: 3.5GB write traffic).
// MODE 0: C = bf16(relu(.+bias)) via per-wave LDS bounce. MODE 1: fused
// coupling epilogue.
// ---------------------------------------------------------------------------
template <int MODE>
__global__ __launch_bounds__(1024, 4)
void gemmk(const unsigned short* __restrict__ A,
           const unsigned short* __restrict__ Bt,
           const float* __restrict__ bias,
           unsigned short* __restrict__ Cout,
           const float* __restrict__ xold, float* __restrict__ xnew,
           float* __restrict__ part, int par,
           int M, int N, int K) {
  __shared__ unsigned short lds[65536];   // 128 KiB (ring uses first 96 KiB)
  char* ldsb = (char*)lds;
  const int tid = threadIdx.x;
  const int w = tid >> 6, lane = tid & 63;
  const int fr = lane & 15, fq = lane >> 4;
  const int wr = w >> 2, wc = w & 3;          // 4M x 4N waves, wave tile 64x64

  // XCD-aware block swizzle (nwg % 8 == 0 for all our grids)
  const int nbx = N >> 8;
  const int nwg = (int)gridDim.x;
  const int cpx = nwg >> 3;
  const int bid = (int)blockIdx.x;
  const int swz = (bid & 7) * cpx + (bid >> 3);
  const int by = swz / nbx, bx = swz - by * nbx;
  const int m0 = by << 8, n0 = bx << 8;

  // read-side swizzled base offsets within a buffer
  const int chunkp = (((fr & 1) << 2) | fq) ^ (fr >> 1);
  const int A0 = (wr * 32 + (fr >> 1)) * 128 + chunkp * 16;           // A slab @0
  const int B0 = 16384 + (wc * 32 + (fr >> 1)) * 128 + chunkp * 16;   // B slab @16KB

  // stage-side: inverse-swizzled per-lane global source; linear LDS dest.
  // 1024 threads x 16B = one full 16KB slab per gload16 call.
  const int p = tid >> 3, cph = tid & 7;
  const int clg = cph ^ (p & 7);            // logical chunk
  const int rowS = 2 * p + (clg >> 2);
  const int kcolS = (clg & 3) * 8;
  const unsigned short* sA0 = A + (size_t)(m0 + rowS) * K + kcolS;
  const unsigned short* sB0 = Bt + (size_t)(n0 + rowS) * K + kcolS;
  const int dst0 = tid * 16;                // byte offset within a slab

// stage one BK=32 tile (A 16KB + B 16KB) into buffer at OFF; advance ptrs
#define STAGE_ALL(OFF) do {                                                  \
    gload16(sA0, ldsb + (OFF) + dst0);                                       \
    gload16(sB0, ldsb + (OFF) + 16384 + dst0);                               \
    sA0 += 32; sB0 += 32;                                                    \
  } while (0)

#define WIN(STG, VM)                                                         \
  {                                                                          \
    __builtin_amdgcn_s_barrier();                                            \
    __builtin_amdgcn_sched_barrier(0);                                       \
    if (STG) STAGE_ALL(stg);                                                 \
    bf16x8 av[4], bv[4];                                                     \
    _Pragma("unroll") for (int n = 0; n < 4; ++n)                            \
      bv[n] = *(const bf16x8*)(ldsb + cur + B0 + n * 1024);                  \
    _Pragma("unroll") for (int m = 0; m < 4; ++m)                            \
      av[m] = *(const bf16x8*)(ldsb + cur + A0 + m * 1024);                  \
    __builtin_amdgcn_s_setprio(1);                                           \
    _Pragma("unroll") for (int m = 0; m < 4; ++m)                            \
      _Pragma("unroll") for (int n = 0; n < 4; ++n)                          \
        acc[m][n] = __builtin_amdgcn_mfma_f32_16x16x32_bf16(                 \
            av[m], bv[n], acc[m][n], 0, 0, 0);                               \
    __builtin_amdgcn_s_setprio(0);                                           \
    if (VM == 1) asm volatile("s_waitcnt vmcnt(2)" ::: "memory");            \
    if (VM == 2) asm volatile("s_waitcnt vmcnt(0)" ::: "memory");            \
    __builtin_amdgcn_sched_barrier(0);                                       \
    cur = (cur == 65536) ? 0 : cur + 32768;                                  \
    stg = (stg == 65536) ? 0 : stg + 32768;                                  \
  }

  f32x4 acc[4][4];
  f32x4 z4 = {0.f, 0.f, 0.f, 0.f};
#pragma unroll
  for (int m = 0; m < 4; ++m)
#pragma unroll
    for (int n = 0; n < 4; ++n) acc[m][n] = z4;

  const int NT = K >> 5;   // BK=32; K % 32 == 0, NT >= 4

  // prologue: stage tile 0 -> buf0, tile 1 -> buf1; confirm tile 0
  STAGE_ALL(0);
  STAGE_ALL(32768);
  asm volatile("s_waitcnt vmcnt(2)" ::: "memory");
  __builtin_amdgcn_sched_barrier(0);
  int cur = 0, stg = 65536;

  for (int T = 0; T < NT - 2; ++T) {
    WIN(1, 1)
  }
  WIN(0, 2)   // T = NT-2: drain tile NT-1
  WIN(0, 0)   // T = NT-1: compute only
#undef WIN
#undef STAGE_ALL

  // ---- epilogue ---- (C/D frag layout: row = fq*4 + r, col = fr; m89/m91)
  if (MODE == 0) {
    // bf16 + relu via per-wave LDS bounce: wave region w*8192 = [64][128B],
    // chunk ^= fq swizzle (<=2-way = free, R4-verified pattern).
    __builtin_amdgcn_s_barrier();   // all waves done reading ring buffers
#pragma unroll
    for (int m = 0; m < 4; ++m)
#pragma unroll
      for (int n = 0; n < 4; ++n) {
        int gcol = n0 + wc * 64 + n * 16 + fr;
        float bb = bias[gcol];
#pragma unroll
        for (int r = 0; r < 4; ++r) {
          float v = fmaxf(acc[m][n][r] + bb, 0.f);
          int lrow = m * 16 + fq * 4 + r;
          *(unsigned short*)(ldsb + w * 8192 + lrow * 128 + ((n ^ fq) * 32) + fr * 2) = f2bf(v);
        }
      }
    asm volatile("s_waitcnt lgkmcnt(0)" ::: "memory");   // own-wave region only
    __builtin_amdgcn_sched_barrier(0);
    unsigned short* Cb = Cout + (size_t)(m0 + wr * 64) * N + n0 + wc * 64;
    const int sub = lane & 7;
#pragma unroll
    for (int i = 0; i < 8; ++i) {
      int lrow = i * 8 + (lane >> 3);
      int phys = (sub >> 1) ^ ((lrow >> 2) & 3);
      bf16x8 val = *(const bf16x8*)(ldsb + w * 8192 + lrow * 128 + phys * 32 + (sub & 1) * 16);
      *(bf16x8*)(Cb + (size_t)lrow * N + sub * 8) = val;
    }
  } else {
    // fused coupling: even col 2j = S, odd = T (pair via shfl_xor 1);
    // xnew[row][2j+par] = xold[row][2j+par]*exp(S)+T; S partials -> part.
#pragma unroll
    for (int m = 0; m < 4; ++m) {
      float srow[4] = {0.f, 0.f, 0.f, 0.f};
#pragma unroll
      for (int n = 0; n < 4; ++n) {
        int gcol = n0 + wc * 64 + n * 16 + fr;
        float bb = bias[gcol];
#pragma unroll
        for (int r = 0; r < 4; ++r) {
          float v = acc[m][n][r] + bb;
          float vp = __shfl_xor(v, 1);
          if (!(fr & 1)) {
            int grow = m0 + wr * 64 + m * 16 + fq * 4 + r;
            size_t idx = (size_t)grow * N + gcol + par;
            xnew[idx] = xold[idx] * expf(v) + vp;
            srow[r] += v;
          }
        }
      }
#pragma unroll
      for (int r = 0; r < 4; ++r) {
        float s = srow[r];
        s += __shfl_xor(s, 2);
        s += __shfl_xor(s, 4);
        s += __shfl_xor(s, 8);
        if (fr == 0) {
          int grow = m0 + wr * 64 + m * 16 + fq * 4 + r;
          part[(size_t)grow * 32 + bx * 4 + wc] = s;
        }
      }
    }
  }
}

// logdet[row] (= or +=) sum of 32 column-group partials
__global__ void reduce_logdet(const float* __restrict__ P, float* __restrict__ logdet, int add) {
  int row = blockIdx.x * 256 + threadIdx.x;
  float s = 0.f;
#pragma unroll
  for (int g = 0; g < 32; ++g) s += P[(size_t)row * 32 + g];
  logdet[row] = add ? (logdet[row] + s) : s;
}

extern "C" void kernel_launch(void* const* d_in, const int* in_sizes, int n_in,
                              void* d_out, int out_size, void* d_ws, size_t ws_size,
                              hipStream_t stream) {
  const float* z    = (const float*)d_in[0];
  const float* cond = (const float*)d_in[1];
  const float* W1   = (const float*)d_in[4];
  const float* b1   = (const float*)d_in[5];
  const float* W2   = (const float*)d_in[6];
  const float* b2   = (const float*)d_in[7];
  const float* W3   = (const float*)d_in[8];
  const float* b3   = (const float*)d_in[9];

  float* xout   = (float*)d_out;                 // [B, D]
  float* logdet = xout + (size_t)B_ * D_;        // [B]

  // workspace (160 MiB): Wt 32 MiB | H1 64 MiB (h1 / logdet partials) |
  //                      H2 64 MiB (A0 input acts / h2)
  char* ws = (char*)d_ws;
  unsigned short* Wt = (unsigned short*)ws;
  unsigned short* H1 = (unsigned short*)(ws + 33554432);
  unsigned short* H2 = (unsigned short*)(ws + 33554432 + 67108864);
  float* Pp = (float*)H1;          // [B][32] S-partials (H1 free during GEMM3)
  unsigned short* A0 = H2;

  for (int blk = 0; blk < 2; ++blk) {
    const float* W1b = W1 + (size_t)blk * KIN_ * H_;
    const float* W2b = W2 + (size_t)blk * H_ * H_;
    const float* W3b = W3 + (size_t)blk * H_ * D_;
    const float* b1b = b1 + (size_t)blk * H_;
    const float* b2b = b2 + (size_t)blk * H_;
    const float* b3b = b3 + (size_t)blk * D_;
    // identity channels parity 1-blk; transformed channels parity blk.
    const float* xsrc = blk ? xout : z;

    // GEMM1: [B,1088] x [1088,4096]
    convT<<<dim3(H_ / 32, KIN_ / 32), 256, 0, stream>>>(W1b, Wt, KIN_, H_);
    build_act<<<dim3(5, B_), 256, 0, stream>>>(xsrc, cond, 1 - blk, A0);
    gemmk<0><<<dim3((B_ / 256) * (H_ / 256)), 1024, 0, stream>>>(
        A0, Wt, b1b, H1, nullptr, nullptr, nullptr, 0, B_, H_, KIN_);

    // GEMM2: [B,4096] x [4096,4096]
    convT<<<dim3(H_ / 32, H_ / 32), 256, 0, stream>>>(W2b, Wt, H_, H_);
    gemmk<0><<<dim3((B_ / 256) * (H_ / 256)), 1024, 0, stream>>>(
        H1, Wt, b2b, H2, nullptr, nullptr, nullptr, 0, B_, H_, H_);

    // GEMM3: [B,4096] x [4096,2048] with fused coupling epilogue
    convT<<<dim3(D_ / 32, H_ / 32), 256, 0, stream>>>(W3b, Wt, H_, D_);
    gemmk<1><<<dim3((B_ / 256) * (D_ / 256)), 1024, 0, stream>>>(
        H2, Wt, b3b, nullptr, z, xout, Pp, blk, B_, D_, H_);

    reduce_logdet<<<dim3(B_ / 256), 256, 0, stream>>>(Pp, logdet, blk);
  }
}